// Round 16
// baseline (215.305 us; speedup 1.0000x reference)
//
#include <hip/hip_runtime.h>

#define NNODES 100000
#define NEDGES 600000
#define NCLASS 26
#define HID    128

#define SHIFT  9
#define BCOLS  512                    // cols per bucket
#define NBKT   196                    // ceil(100000/512)
#define EPB    1024                   // edges per partition block
#define NBE    586                    // ceil(600000/1024)
#define NH     (NBKT * NBE)           // 114856 histogram cells

typedef __attribute__((ext_vector_type(8))) short bf16x8;
typedef __attribute__((ext_vector_type(4))) float f32x4;

__device__ inline unsigned short f2bf(float f) {  // RNE fp32->bf16
    unsigned int u = __float_as_uint(f);
    u += 0x7fffu + ((u >> 16) & 1u);
    return (unsigned short)(u >> 16);
}
__device__ inline unsigned int packbf(float a, float b) {
    return (unsigned int)f2bf(a) | ((unsigned int)f2bf(b) << 16);
}
__device__ inline float2 bfpair(unsigned int p) {
    float2 r;
    r.x = __uint_as_float(p << 16);
    r.y = __uint_as_float(p & 0xffff0000u);
    return r;
}

// ---- pass A: per-block LDS histogram of edge->bucket ----
__global__ __launch_bounds__(256) void histA_k(const int* __restrict__ col,
                                               int* __restrict__ H) {
    __shared__ int h[NBKT];
    int t = threadIdx.x;
    for (int i = t; i < NBKT; i += 256) h[i] = 0;
    __syncthreads();
    int base = blockIdx.x * EPB;
#pragma unroll
    for (int u = 0; u < 4; u++) {
        int e = base + t + u * 256;
        if (e < NEDGES) atomicAdd(&h[col[e] >> SHIFT], 1);
    }
    __syncthreads();
    for (int i = t; i < NBKT; i += 256) H[i * NBE + blockIdx.x] = h[i];
}

__global__ void scanH1_k(const int* __restrict__ in, int* __restrict__ incl,
                         int* __restrict__ aux, int n) {
    __shared__ int s[256];
    int t = threadIdx.x, gi = blockIdx.x * 256 + t;
    s[t] = (gi < n) ? in[gi] : 0;
    __syncthreads();
    for (int off = 1; off < 256; off <<= 1) {
        int x = (t >= off) ? s[t - off] : 0;
        __syncthreads();
        s[t] += x;
        __syncthreads();
    }
    if (gi < n) incl[gi] = s[t];
    if (t == 255) aux[blockIdx.x] = s[255];
}

__global__ void scan2_k(int* __restrict__ aux, int n) {  // 1 block, 512 thr
    __shared__ int s[512];
    int t = threadIdx.x;
    s[t] = (t < n) ? aux[t] : 0;
    __syncthreads();
    for (int off = 1; off < 512; off <<= 1) {
        int x = (t >= off) ? s[t - off] : 0;
        __syncthreads();
        s[t] += x;
        __syncthreads();
    }
    if (t < n) aux[t] = s[t];
}

// exclusive offset of cell gi, reconstructed from incl/H/aux
__device__ inline int exoff(const int* __restrict__ incl, const int* __restrict__ H,
                            const int* __restrict__ aux, int gi) {
    int add = (gi >= 256) ? aux[(gi >> 8) - 1] : 0;
    return incl[gi] - H[gi] + add;
}

// ---- pass B: partition edges into bucket-contiguous storage ----
__global__ __launch_bounds__(256) void partB_k(const int* __restrict__ row,
                                               const int* __restrict__ col,
                                               const float* __restrict__ w,
                                               const int* __restrict__ incl,
                                               const int* __restrict__ H,
                                               const int* __restrict__ aux,
                                               uint2* __restrict__ rw,
                                               unsigned short* __restrict__ lc) {
    __shared__ int off[NBKT];
    __shared__ int cur[NBKT];
    int t = threadIdx.x;
    for (int i = t; i < NBKT; i += 256) {
        off[i] = exoff(incl, H, aux, i * NBE + blockIdx.x);
        cur[i] = 0;
    }
    __syncthreads();
    int base = blockIdx.x * EPB;
#pragma unroll
    for (int u = 0; u < 4; u++) {
        int e = base + t + u * 256;
        if (e < NEDGES) {
            int c = col[e], b = c >> SHIFT;
            int p = off[b] + atomicAdd(&cur[b], 1);
            rw[p] = make_uint2((unsigned int)row[e], __float_as_uint(w[e]));
            lc[p] = (unsigned short)(c & (BCOLS - 1));
        }
    }
}

// ---- fused per-bucket: degree/wsum -> dis + rowptr (LDS scan) -> place meta ----
__global__ __launch_bounds__(256) void segbp_k(const uint2* __restrict__ rw,
                                               const unsigned short* __restrict__ lc,
                                               const int* __restrict__ incl,
                                               const int* __restrict__ H,
                                               const int* __restrict__ aux,
                                               int* __restrict__ rowptr,
                                               float* __restrict__ dis,
                                               uint2* __restrict__ meta) {
    __shared__ int   cnt[BCOLS];
    __shared__ float ws[BCOLS];
    __shared__ int   rpl[BCOLS];
    __shared__ int   ps[256];
    int b = blockIdx.x, t = threadIdx.x;
    int c0 = b << SHIFT;
    int ncols = min(BCOLS, NNODES - c0);
    for (int i = t; i < BCOLS; i += 256) { cnt[i] = 0; ws[i] = 0.f; }
    __syncthreads();
    int s    = exoff(incl, H, aux, b * NBE);
    int eend = (b == NBKT - 1) ? NEDGES : exoff(incl, H, aux, (b + 1) * NBE);
    for (int e = s + t; e < eend; e += 256) {
        uint2 m = rw[e];
        int l = lc[e];
        atomicAdd(&cnt[l], 1);
        atomicAdd(&ws[l], __uint_as_float(m.y));
    }
    __syncthreads();
    for (int i = t; i < ncols; i += 256) dis[c0 + i] = rsqrtf(1.0f + ws[i]);
    int a0 = cnt[2 * t], a1 = cnt[2 * t + 1];
    ps[t] = a0 + a1;
    __syncthreads();
    for (int off = 1; off < 256; off <<= 1) {
        int x = (t >= off) ? ps[t - off] : 0;
        __syncthreads();
        ps[t] += x;
        __syncthreads();
    }
    int ex = (t > 0) ? ps[t - 1] : 0;
    rpl[2 * t]     = s + ex;
    rpl[2 * t + 1] = s + ex + a0;
    if (2 * t     < ncols) rowptr[c0 + 2 * t]     = s + ex;
    if (2 * t + 1 < ncols) rowptr[c0 + 2 * t + 1] = s + ex + a0;
    if (b == NBKT - 1 && t == 0) rowptr[NNODES] = NEDGES;
    cnt[2 * t] = 0; cnt[2 * t + 1] = 0;   // reuse as cursors
    __syncthreads();
    for (int e = s + t; e < eend; e += 256) {
        uint2 m = rw[e];
        int l = lc[e];
        int pos = rpl[l] + atomicAdd(&cnt[l], 1);
        meta[pos] = make_uint2(m.x, m.y);   // (src, w)
    }
}

// ---- fused prep: W2^T bf16 | W1^T padded bf16 | Wfc^T padded bf16 | xs = dis*x ----
__global__ __launch_bounds__(256) void prep_k(const float* __restrict__ W2,
                                              const float* __restrict__ W1,
                                              const float* __restrict__ Wfc,
                                              const float* __restrict__ x,
                                              const float* __restrict__ dis,
                                              unsigned short* __restrict__ wt,
                                              unsigned short* __restrict__ w1t,
                                              unsigned short* __restrict__ wfct,
                                              unsigned int* __restrict__ xp) {
    int b = blockIdx.x, t = threadIdx.x;
    if (b < 64) {
        int idx = b * 256 + t;
        int c = idx >> 7, k = idx & 127;
        wt[c * 128 + k] = f2bf(W2[k * 128 + c]);
    } else if (b < 80) {
        int idx = (b - 64) * 256 + t;
        int c = idx >> 5, k = idx & 31;
        w1t[c * 32 + k] = (k < NCLASS) ? f2bf(W1[k * 128 + c]) : (unsigned short)0;
    } else if (b < 96) {
        int idx = (b - 80) * 256 + t;
        int c = idx >> 7, k = idx & 127;
        wfct[c * 128 + k] = (c < NCLASS) ? f2bf(Wfc[k * NCLASS + c]) : (unsigned short)0;
    } else {
        int i = (b - 96) * 256 + t;
        if (i < NNODES * 16) {
            int r = i >> 4, u = i & 15, f0 = u * 2;
            float d = dis[r];
            float a = (f0     < NCLASS) ? x[r * NCLASS + f0]     : 0.f;
            float c = (f0 + 1 < NCLASS) ? x[r * NCLASS + f0 + 1] : 0.f;
            xp[i] = packbf(d * a, d * c);
        }
    }
}

// ---- agg 26-dim (standalone, high-occupancy): aggx = d_dst*(xs[dst]+sum w*xs[src]) ----
__global__ __launch_bounds__(256) void agg26_k(const int* __restrict__ rowptr,
                                               const uint2* __restrict__ meta,
                                               const unsigned int* __restrict__ xp,
                                               const float* __restrict__ dis,
                                               unsigned int* __restrict__ aggx) {
    int node = blockIdx.x * 16 + (threadIdx.x >> 4);
    int lane = threadIdx.x & 15;

    float2 acc = bfpair(xp[node * 16 + lane]);
    int j = rowptr[node], jend = rowptr[node + 1];
    for (; j + 3 < jend; j += 4) {
        uint2 m0 = meta[j],     m1 = meta[j + 1];
        uint2 m2 = meta[j + 2], m3 = meta[j + 3];
        unsigned int g0 = xp[m0.x * 16 + lane];
        unsigned int g1 = xp[m1.x * 16 + lane];
        unsigned int g2 = xp[m2.x * 16 + lane];
        unsigned int g3 = xp[m3.x * 16 + lane];
        float v0 = __uint_as_float(m0.y), v1 = __uint_as_float(m1.y);
        float v2 = __uint_as_float(m2.y), v3 = __uint_as_float(m3.y);
        float2 a;
        a = bfpair(g0); acc.x = fmaf(v0, a.x, acc.x); acc.y = fmaf(v0, a.y, acc.y);
        a = bfpair(g1); acc.x = fmaf(v1, a.x, acc.x); acc.y = fmaf(v1, a.y, acc.y);
        a = bfpair(g2); acc.x = fmaf(v2, a.x, acc.x); acc.y = fmaf(v2, a.y, acc.y);
        a = bfpair(g3); acc.x = fmaf(v3, a.x, acc.x); acc.y = fmaf(v3, a.y, acc.y);
    }
    for (; j < jend; j++) {
        uint2 m = meta[j];
        float v = __uint_as_float(m.y);
        float2 a = bfpair(xp[m.x * 16 + lane]);
        acc.x = fmaf(v, a.x, acc.x); acc.y = fmaf(v, a.y, acc.y);
    }
    float d = dis[node];
    aggx[node * 16 + lane] = packbf(d * acc.x, d * acc.y);
}

// ---- fused gemm1+gemm2 (r13 128-row, Ws-staged): t2s = dis*(relu(aggx@W1+b1)@W2) ----
__global__ __launch_bounds__(256) void gemm12_k(const unsigned short* __restrict__ aggx,
                                                const unsigned short* __restrict__ w1t,
                                                const float* __restrict__ b1,
                                                const unsigned short* __restrict__ wt,
                                                const float* __restrict__ dis,
                                                unsigned short* __restrict__ C, int N) {
    __shared__ unsigned short h1s[128 * 136];  // h1 tile, stride 136
    __shared__ unsigned short Ws[128 * 72];    // W2^T k-chunk staging
    const int tid  = threadIdx.x;
    const int wave = tid >> 6, lane = tid & 63;
    const int quad = lane >> 4, l16 = lane & 15;
    const int wm = wave >> 1, wn = wave & 1;
    const int row0 = blockIdx.x * 128;

    // ---- phase 1: h1 = relu(aggx @ W1 + b1) into LDS ----
    bf16x8 a1[4], bw1[4];
#pragma unroll
    for (int t = 0; t < 4; t++) {
        int r = row0 + wm * 64 + t * 16 + l16;
        a1[t] = (r < N) ? *(const bf16x8*)&aggx[(size_t)r * 32 + quad * 8]
                        : (bf16x8)(short)0;
        bw1[t] = *(const bf16x8*)&w1t[(wn * 64 + t * 16 + l16) * 32 + quad * 8];
    }
#pragma unroll
    for (int jj = 0; jj < 4; jj++) {
        int idx = tid + jj * 256;
        int r = idx >> 3, ku = idx & 7;
        *(uint4*)&Ws[r * 72 + ku * 8] = *(const uint4*)&wt[(size_t)r * 128 + ku * 8];
    }
    float b1v[4];
#pragma unroll
    for (int tn = 0; tn < 4; tn++) b1v[tn] = b1[wn * 64 + tn * 16 + l16];
#pragma unroll
    for (int tm = 0; tm < 4; tm++) {
#pragma unroll
        for (int tn = 0; tn < 4; tn++) {
            f32x4 hacc = __builtin_amdgcn_mfma_f32_16x16x32_bf16(
                a1[tm], bw1[tn], (f32x4)0.f, 0, 0, 0);
            int rl = wm * 64 + tm * 16 + quad * 4;
            int col = wn * 64 + tn * 16 + l16;
#pragma unroll
            for (int r = 0; r < 4; r++)
                h1s[(rl + r) * 136 + col] = f2bf(fmaxf(hacc[r] + b1v[tn], 0.f));
        }
    }
    __syncthreads();

    // ---- phase 2: K-loop over h1s @ W2 ----
    f32x4 acc[4][4];
#pragma unroll
    for (int i = 0; i < 4; i++)
#pragma unroll
        for (int j = 0; j < 4; j++) acc[i][j] = (f32x4)0.f;

    for (int c = 0; c < 2; c++) {
        if (c == 1) {
            __syncthreads();
#pragma unroll
            for (int jj = 0; jj < 4; jj++) {
                int idx = tid + jj * 256;
                int r = idx >> 3, ku = idx & 7;
                *(uint4*)&Ws[r * 72 + ku * 8] =
                    *(const uint4*)&wt[(size_t)r * 128 + 64 + ku * 8];
            }
            __syncthreads();
        }
#pragma unroll
        for (int kc = 0; kc < 2; kc++) {
            const int klA = c * 64 + kc * 32 + quad * 8;
            const int klW = kc * 32 + quad * 8;
            bf16x8 af[4], bfr[4];
#pragma unroll
            for (int t = 0; t < 4; t++) {
                af[t]  = *(const bf16x8*)&h1s[(wm * 64 + t * 16 + l16) * 136 + klA];
                bfr[t] = *(const bf16x8*)&Ws[(wn * 64 + t * 16 + l16) * 72 + klW];
            }
#pragma unroll
            for (int tm = 0; tm < 4; tm++)
#pragma unroll
                for (int tn = 0; tn < 4; tn++)
                    acc[tm][tn] = __builtin_amdgcn_mfma_f32_16x16x32_bf16(
                        af[tm], bfr[tn], acc[tm][tn], 0, 0, 0);
        }
    }

#pragma unroll
    for (int tm = 0; tm < 4; tm++) {
        const int rbase = row0 + wm * 64 + tm * 16 + quad * 4;
        float dv[4];
#pragma unroll
        for (int r = 0; r < 4; r++)
            dv[r] = (rbase + r < N) ? dis[rbase + r] : 0.f;
#pragma unroll
        for (int tn = 0; tn < 4; tn++) {
            const int col = wn * 64 + tn * 16 + l16;
#pragma unroll
            for (int r = 0; r < 4; r++) {
                if (rbase + r < N)
                    C[(size_t)(rbase + r) * 128 + col] = f2bf(dv[r] * acc[tm][tn][r]);
            }
        }
    }
}

// ---- fused agg128 + fc, wave-private, 1 node/wave gather (r6-proven balance):
// wave wv fills rows wv*16+p (p=0..15), one node per pass, 64 lanes x uint (2 feats).
// Per-pass trip count = own degree (no max-over-nodes divergence); no barrier. ----
__global__ __launch_bounds__(256) void aggfc_k(const int* __restrict__ rowptr,
                                               const uint2* __restrict__ meta,
                                               const unsigned int* __restrict__ h,
                                               const float* __restrict__ dis,
                                               const float* __restrict__ b2,
                                               const unsigned short* __restrict__ wfct,
                                               const float* __restrict__ bfc,
                                               float* __restrict__ out, int N) {
    __shared__ unsigned short h2s[64 * 136];
    const int tid = threadIdx.x;
    const int wv = tid >> 6, lane = tid & 63;
    const int nbase = blockIdx.x * 64;

    // ---- gather phase: wave wv fills its rows wv*16 .. wv*16+15 ----
    for (int p = 0; p < 16; p++) {
        int r = wv * 16 + p;
        int node = nbase + r;
        float2 acc = make_float2(0.f, 0.f);
        float d = 0.f;
        if (node < N) {
            d = dis[node];
            acc = bfpair(h[(size_t)node * 64 + lane]);
            int j = rowptr[node], jend = rowptr[node + 1];
            for (; j + 3 < jend; j += 4) {
                uint2 m0 = meta[j],     m1 = meta[j + 1];
                uint2 m2 = meta[j + 2], m3 = meta[j + 3];
                unsigned int g0 = h[(size_t)m0.x * 64 + lane];
                unsigned int g1 = h[(size_t)m1.x * 64 + lane];
                unsigned int g2 = h[(size_t)m2.x * 64 + lane];
                unsigned int g3 = h[(size_t)m3.x * 64 + lane];
                float v0 = __uint_as_float(m0.y), v1 = __uint_as_float(m1.y);
                float v2 = __uint_as_float(m2.y), v3 = __uint_as_float(m3.y);
                float2 a;
                a = bfpair(g0); acc.x = fmaf(v0, a.x, acc.x); acc.y = fmaf(v0, a.y, acc.y);
                a = bfpair(g1); acc.x = fmaf(v1, a.x, acc.x); acc.y = fmaf(v1, a.y, acc.y);
                a = bfpair(g2); acc.x = fmaf(v2, a.x, acc.x); acc.y = fmaf(v2, a.y, acc.y);
                a = bfpair(g3); acc.x = fmaf(v3, a.x, acc.x); acc.y = fmaf(v3, a.y, acc.y);
            }
            for (; j < jend; j++) {
                uint2 m = meta[j];
                float v = __uint_as_float(m.y);
                float2 a = bfpair(h[(size_t)m.x * 64 + lane]);
                acc.x = fmaf(v, a.x, acc.x); acc.y = fmaf(v, a.y, acc.y);
            }
        }
        float2 bv = ((const float2*)b2)[lane];
        acc.x = fmaxf(fmaf(d, acc.x, bv.x), 0.f);
        acc.y = fmaxf(fmaf(d, acc.y, bv.y), 0.f);
        if (node >= N) { acc.x = 0.f; acc.y = 0.f; }
        *(unsigned int*)&h2s[r * 136 + lane * 2] = packbf(acc.x, acc.y);
    }
    // no __syncthreads(): each wave reads back only the rows it wrote

    // ---- fc phase: wave wv handles its rows wv*16..+15 ----
    const int q = lane >> 4, m = lane & 15;
    bf16x8 af[4];
#pragma unroll
    for (int ks = 0; ks < 4; ks++)
        af[ks] = *(const bf16x8*)&h2s[(wv * 16 + m) * 136 + ks * 32 + q * 8];

#pragma unroll
    for (int n = 0; n < 2; n++) {
        f32x4 o = (f32x4)0.f;
#pragma unroll
        for (int ks = 0; ks < 4; ks++) {
            bf16x8 bfr = *(const bf16x8*)&wfct[(size_t)(n * 16 + m) * 128 + ks * 32 + q * 8];
            o = __builtin_amdgcn_mfma_f32_16x16x32_bf16(af[ks], bfr, o, 0, 0, 0);
        }
        int col = n * 16 + m;
        if (col < NCLASS) {
            float bv = bfc[col];
            int r0 = nbase + wv * 16 + q * 4;
#pragma unroll
            for (int r = 0; r < 4; r++) {
                if (r0 + r < N)
                    out[(size_t)(r0 + r) * NCLASS + col] = o[r] + bv;
            }
        }
    }
}

extern "C" void kernel_launch(void* const* d_in, const int* in_sizes, int n_in,
                              void* d_out, int out_size, void* d_ws, size_t ws_size,
                              hipStream_t stream) {
    const float* x   = (const float*)d_in[0];
    const int*   ei  = (const int*)d_in[1];
    const float* ew  = (const float*)d_in[2];
    const float* W1  = (const float*)d_in[3];
    const float* b1  = (const float*)d_in[4];
    const float* W2  = (const float*)d_in[5];
    const float* b2  = (const float*)d_in[6];
    const float* Wfc = (const float*)d_in[7];
    const float* bfc = (const float*)d_in[8];
    float* out = (float*)d_out;

    const int N = NNODES;
    const int* erow = ei;
    const int* ecol = ei + NEDGES;

    // ws layout (float-unit offsets):
    float* fws    = (float*)d_ws;
    float* dis    = fws;                                       // 100000
    int*   rowptr = (int*)(fws + 100000);                      // 100001 (+pad)
    int*   H      = (int*)(fws + 200004);                      // 114856
    int*   incl   = (int*)(fws + 314860);                      // 114856
    int*   aux    = (int*)(fws + 429716);                      // 512
    uint2* rw     = (uint2*)(fws + 430228);                    // 600000 uint2
    unsigned short* lc = (unsigned short*)(fws + 1630228);     // 600000 u16
    uint2* meta   = (uint2*)(fws + 1930228);                   // 600000 uint2
    unsigned short* wt16   = (unsigned short*)(fws + 3130228); // 128*128
    unsigned short* w1t16  = (unsigned short*)(fws + 3138420); // 128*32
    unsigned short* wfct16 = (unsigned short*)(fws + 3140468); // 32*128
    unsigned int*   xp     = (unsigned int*)(fws + 3142516);   // N*16
    unsigned int*   aggx   = (unsigned int*)(fws + 4742516);   // N*16
    unsigned short* hB16   = (unsigned short*)(fws + 6342516); // N*128 bf16 (t2s)

    const int gScan = (NH + 255) / 256;   // 449
    const int g128  = (N + 127) / 128;    // 782
    const int gA26  = N / 16;             // 6250
    const int gPrep = 96 + (N * 16 + 255) / 256;
    const int gFc   = (N + 63) / 64;      // 1563

    // ---- CSR build (5 kernels) ----
    histA_k<<<NBE, 256, 0, stream>>>(ecol, H);
    scanH1_k<<<gScan, 256, 0, stream>>>(H, incl, aux, NH);
    scan2_k<<<1, 512, 0, stream>>>(aux, gScan);
    partB_k<<<NBE, 256, 0, stream>>>(erow, ecol, ew, incl, H, aux, rw, lc);
    segbp_k<<<NBKT, 256, 0, stream>>>(rw, lc, incl, H, aux, rowptr, dis, meta);

    // ---- prep ----
    prep_k<<<gPrep, 256, 0, stream>>>(W2, W1, Wfc, x, dis, wt16, w1t16, wfct16, xp);

    // ---- layer 1 agg (standalone, high-occupancy) -> fused gemm1+gemm2 ----
    agg26_k<<<gA26, 256, 0, stream>>>(rowptr, meta, xp, dis, aggx);
    gemm12_k<<<g128, 256, 0, stream>>>((const unsigned short*)aggx, w1t16, b1,
                                       wt16, dis, hB16, N);

    // ---- fused agg128 + fc (wave-private, 1 node/wave, barrier-free) ----
    aggfc_k<<<gFc, 256, 0, stream>>>(rowptr, meta, (const unsigned int*)hB16, dis, b2,
                                     wfct16, bfc, out, N);
}

// Round 17
// 200.390 us; speedup vs baseline: 1.0744x; 1.0744x over previous
//
#include <hip/hip_runtime.h>

#define NNODES 100000
#define NEDGES 600000
#define NCLASS 26
#define HID    128

#define SHIFT  9
#define BCOLS  512                    // cols per bucket
#define NBKT   196                    // ceil(100000/512)
#define EPB    1024                   // edges per partition block
#define NBE    586                    // ceil(600000/1024)
#define NH     (NBKT * NBE)           // 114856 histogram cells

typedef __attribute__((ext_vector_type(8))) short bf16x8;
typedef __attribute__((ext_vector_type(4))) float f32x4;

__device__ inline unsigned short f2bf(float f) {  // RNE fp32->bf16
    unsigned int u = __float_as_uint(f);
    u += 0x7fffu + ((u >> 16) & 1u);
    return (unsigned short)(u >> 16);
}
__device__ inline unsigned int packbf(float a, float b) {
    return (unsigned int)f2bf(a) | ((unsigned int)f2bf(b) << 16);
}
__device__ inline float2 bfpair(unsigned int p) {
    float2 r;
    r.x = __uint_as_float(p << 16);
    r.y = __uint_as_float(p & 0xffff0000u);
    return r;
}

// ---- pass A: per-block LDS histogram of edge->bucket ----
__global__ __launch_bounds__(256) void histA_k(const int* __restrict__ col,
                                               int* __restrict__ H) {
    __shared__ int h[NBKT];
    int t = threadIdx.x;
    for (int i = t; i < NBKT; i += 256) h[i] = 0;
    __syncthreads();
    int base = blockIdx.x * EPB;
#pragma unroll
    for (int u = 0; u < 4; u++) {
        int e = base + t + u * 256;
        if (e < NEDGES) atomicAdd(&h[col[e] >> SHIFT], 1);
    }
    __syncthreads();
    for (int i = t; i < NBKT; i += 256) H[i * NBE + blockIdx.x] = h[i];
}

__global__ void scanH1_k(const int* __restrict__ in, int* __restrict__ incl,
                         int* __restrict__ aux, int n) {
    __shared__ int s[256];
    int t = threadIdx.x, gi = blockIdx.x * 256 + t;
    s[t] = (gi < n) ? in[gi] : 0;
    __syncthreads();
    for (int off = 1; off < 256; off <<= 1) {
        int x = (t >= off) ? s[t - off] : 0;
        __syncthreads();
        s[t] += x;
        __syncthreads();
    }
    if (gi < n) incl[gi] = s[t];
    if (t == 255) aux[blockIdx.x] = s[255];
}

__global__ void scan2_k(int* __restrict__ aux, int n) {  // 1 block, 512 thr
    __shared__ int s[512];
    int t = threadIdx.x;
    s[t] = (t < n) ? aux[t] : 0;
    __syncthreads();
    for (int off = 1; off < 512; off <<= 1) {
        int x = (t >= off) ? s[t - off] : 0;
        __syncthreads();
        s[t] += x;
        __syncthreads();
    }
    if (t < n) aux[t] = s[t];
}

// exclusive offset of cell gi, reconstructed from incl/H/aux
__device__ inline int exoff(const int* __restrict__ incl, const int* __restrict__ H,
                            const int* __restrict__ aux, int gi) {
    int add = (gi >= 256) ? aux[(gi >> 8) - 1] : 0;
    return incl[gi] - H[gi] + add;
}

// ---- pass B: partition edges into bucket-contiguous storage ----
__global__ __launch_bounds__(256) void partB_k(const int* __restrict__ row,
                                               const int* __restrict__ col,
                                               const float* __restrict__ w,
                                               const int* __restrict__ incl,
                                               const int* __restrict__ H,
                                               const int* __restrict__ aux,
                                               uint2* __restrict__ rw,
                                               unsigned short* __restrict__ lc) {
    __shared__ int off[NBKT];
    __shared__ int cur[NBKT];
    int t = threadIdx.x;
    for (int i = t; i < NBKT; i += 256) {
        off[i] = exoff(incl, H, aux, i * NBE + blockIdx.x);
        cur[i] = 0;
    }
    __syncthreads();
    int base = blockIdx.x * EPB;
#pragma unroll
    for (int u = 0; u < 4; u++) {
        int e = base + t + u * 256;
        if (e < NEDGES) {
            int c = col[e], b = c >> SHIFT;
            int p = off[b] + atomicAdd(&cur[b], 1);
            rw[p] = make_uint2((unsigned int)row[e], __float_as_uint(w[e]));
            lc[p] = (unsigned short)(c & (BCOLS - 1));
        }
    }
}

// ---- fused per-bucket: degree/wsum -> dis + rowptr (LDS scan) -> place meta ----
__global__ __launch_bounds__(256) void segbp_k(const uint2* __restrict__ rw,
                                               const unsigned short* __restrict__ lc,
                                               const int* __restrict__ incl,
                                               const int* __restrict__ H,
                                               const int* __restrict__ aux,
                                               int* __restrict__ rowptr,
                                               float* __restrict__ dis,
                                               uint2* __restrict__ meta) {
    __shared__ int   cnt[BCOLS];
    __shared__ float ws[BCOLS];
    __shared__ int   rpl[BCOLS];
    __shared__ int   ps[256];
    int b = blockIdx.x, t = threadIdx.x;
    int c0 = b << SHIFT;
    int ncols = min(BCOLS, NNODES - c0);
    for (int i = t; i < BCOLS; i += 256) { cnt[i] = 0; ws[i] = 0.f; }
    __syncthreads();
    int s    = exoff(incl, H, aux, b * NBE);
    int eend = (b == NBKT - 1) ? NEDGES : exoff(incl, H, aux, (b + 1) * NBE);
    for (int e = s + t; e < eend; e += 256) {
        uint2 m = rw[e];
        int l = lc[e];
        atomicAdd(&cnt[l], 1);
        atomicAdd(&ws[l], __uint_as_float(m.y));
    }
    __syncthreads();
    for (int i = t; i < ncols; i += 256) dis[c0 + i] = rsqrtf(1.0f + ws[i]);
    int a0 = cnt[2 * t], a1 = cnt[2 * t + 1];
    ps[t] = a0 + a1;
    __syncthreads();
    for (int off = 1; off < 256; off <<= 1) {
        int x = (t >= off) ? ps[t - off] : 0;
        __syncthreads();
        ps[t] += x;
        __syncthreads();
    }
    int ex = (t > 0) ? ps[t - 1] : 0;
    rpl[2 * t]     = s + ex;
    rpl[2 * t + 1] = s + ex + a0;
    if (2 * t     < ncols) rowptr[c0 + 2 * t]     = s + ex;
    if (2 * t + 1 < ncols) rowptr[c0 + 2 * t + 1] = s + ex + a0;
    if (b == NBKT - 1 && t == 0) rowptr[NNODES] = NEDGES;
    cnt[2 * t] = 0; cnt[2 * t + 1] = 0;   // reuse as cursors
    __syncthreads();
    for (int e = s + t; e < eend; e += 256) {
        uint2 m = rw[e];
        int l = lc[e];
        int pos = rpl[l] + atomicAdd(&cnt[l], 1);
        meta[pos] = make_uint2(m.x, m.y);   // (src, w)
    }
}

// ---- fused prep: W2^T bf16 | W1^T padded bf16 | Wfc^T padded bf16 | xs = dis*x ----
__global__ __launch_bounds__(256) void prep_k(const float* __restrict__ W2,
                                              const float* __restrict__ W1,
                                              const float* __restrict__ Wfc,
                                              const float* __restrict__ x,
                                              const float* __restrict__ dis,
                                              unsigned short* __restrict__ wt,
                                              unsigned short* __restrict__ w1t,
                                              unsigned short* __restrict__ wfct,
                                              unsigned int* __restrict__ xp) {
    int b = blockIdx.x, t = threadIdx.x;
    if (b < 64) {
        int idx = b * 256 + t;
        int c = idx >> 7, k = idx & 127;
        wt[c * 128 + k] = f2bf(W2[k * 128 + c]);
    } else if (b < 80) {
        int idx = (b - 64) * 256 + t;
        int c = idx >> 5, k = idx & 31;
        w1t[c * 32 + k] = (k < NCLASS) ? f2bf(W1[k * 128 + c]) : (unsigned short)0;
    } else if (b < 96) {
        int idx = (b - 80) * 256 + t;
        int c = idx >> 7, k = idx & 127;
        wfct[c * 128 + k] = (c < NCLASS) ? f2bf(Wfc[k * NCLASS + c]) : (unsigned short)0;
    } else {
        int i = (b - 96) * 256 + t;
        if (i < NNODES * 16) {
            int r = i >> 4, u = i & 15, f0 = u * 2;
            float d = dis[r];
            float a = (f0     < NCLASS) ? x[r * NCLASS + f0]     : 0.f;
            float c = (f0 + 1 < NCLASS) ? x[r * NCLASS + f0 + 1] : 0.f;
            xp[i] = packbf(d * a, d * c);
        }
    }
}

// ---- agg 26-dim (standalone, high-occupancy): aggx = d_dst*(xs[dst]+sum w*xs[src]) ----
__global__ __launch_bounds__(256) void agg26_k(const int* __restrict__ rowptr,
                                               const uint2* __restrict__ meta,
                                               const unsigned int* __restrict__ xp,
                                               const float* __restrict__ dis,
                                               unsigned int* __restrict__ aggx) {
    int node = blockIdx.x * 16 + (threadIdx.x >> 4);
    int lane = threadIdx.x & 15;

    float2 acc = bfpair(xp[node * 16 + lane]);
    int j = rowptr[node], jend = rowptr[node + 1];
    for (; j + 3 < jend; j += 4) {
        uint2 m0 = meta[j],     m1 = meta[j + 1];
        uint2 m2 = meta[j + 2], m3 = meta[j + 3];
        unsigned int g0 = xp[m0.x * 16 + lane];
        unsigned int g1 = xp[m1.x * 16 + lane];
        unsigned int g2 = xp[m2.x * 16 + lane];
        unsigned int g3 = xp[m3.x * 16 + lane];
        float v0 = __uint_as_float(m0.y), v1 = __uint_as_float(m1.y);
        float v2 = __uint_as_float(m2.y), v3 = __uint_as_float(m3.y);
        float2 a;
        a = bfpair(g0); acc.x = fmaf(v0, a.x, acc.x); acc.y = fmaf(v0, a.y, acc.y);
        a = bfpair(g1); acc.x = fmaf(v1, a.x, acc.x); acc.y = fmaf(v1, a.y, acc.y);
        a = bfpair(g2); acc.x = fmaf(v2, a.x, acc.x); acc.y = fmaf(v2, a.y, acc.y);
        a = bfpair(g3); acc.x = fmaf(v3, a.x, acc.x); acc.y = fmaf(v3, a.y, acc.y);
    }
    for (; j < jend; j++) {
        uint2 m = meta[j];
        float v = __uint_as_float(m.y);
        float2 a = bfpair(xp[m.x * 16 + lane]);
        acc.x = fmaf(v, a.x, acc.x); acc.y = fmaf(v, a.y, acc.y);
    }
    float d = dis[node];
    aggx[node * 16 + lane] = packbf(d * acc.x, d * acc.y);
}

// ---- fused gemm1+gemm2, 64-row tile, Ws-STAGED (r14 lesson), wave-private h1s ----
// LDS 35.8 KB -> 4 blocks/CU (vs 53 KB / 3). t2s = dis*(relu(aggx@W1+b1)@W2).
__global__ __launch_bounds__(256) void gemm12_k(const unsigned short* __restrict__ aggx,
                                                const unsigned short* __restrict__ w1t,
                                                const float* __restrict__ b1,
                                                const unsigned short* __restrict__ wt,
                                                const float* __restrict__ dis,
                                                unsigned short* __restrict__ C, int N) {
    __shared__ unsigned short h1s[64 * 136];   // 17408 B, wave-private rows
    __shared__ unsigned short Ws[128 * 72];    // 18432 B, W2^T K-chunk (64)
    const int tid  = threadIdx.x;
    const int wv = tid >> 6, lane = tid & 63;
    const int quad = lane >> 4, l16 = lane & 15;
    const int row0 = blockIdx.x * 64;
    const int wrow = wv * 16;

    // stage Ws chunk c=0 (K 0..63)
#pragma unroll
    for (int jj = 0; jj < 4; jj++) {
        int idx = tid + jj * 256;
        int r = idx >> 3, ku = idx & 7;
        *(uint4*)&Ws[r * 72 + ku * 8] = *(const uint4*)&wt[(size_t)r * 128 + ku * 8];
    }

    // ---- phase 1: wave's 16 rows of h1 = relu(aggx @ W1 + b1) into its LDS rows ----
    {
        int ar = row0 + wrow + l16;
        bf16x8 af1 = (ar < N) ? *(const bf16x8*)&aggx[(size_t)ar * 32 + quad * 8]
                              : (bf16x8)(short)0;
#pragma unroll
        for (int n = 0; n < 8; n++) {
            bf16x8 bw = *(const bf16x8*)&w1t[(n * 16 + l16) * 32 + quad * 8];
            f32x4 hacc = __builtin_amdgcn_mfma_f32_16x16x32_bf16(af1, bw, (f32x4)0.f, 0, 0, 0);
            int col = n * 16 + l16;
            float bv = b1[col];
#pragma unroll
            for (int r = 0; r < 4; r++)
                h1s[(wrow + quad * 4 + r) * 136 + col] = f2bf(fmaxf(hacc[r] + bv, 0.f));
        }
    }
    __syncthreads();   // Ws c=0 visible (h1s rows are wave-private)

    // ---- phase 2: wave's 16 rows @ W2, K in two staged chunks ----
    bf16x8 af[4];
#pragma unroll
    for (int kc = 0; kc < 4; kc++)
        af[kc] = *(const bf16x8*)&h1s[(wrow + l16) * 136 + kc * 32 + quad * 8];

    f32x4 acc[8];
#pragma unroll
    for (int n = 0; n < 8; n++) acc[n] = (f32x4)0.f;

    for (int c = 0; c < 2; c++) {
        if (c == 1) {
            __syncthreads();
#pragma unroll
            for (int jj = 0; jj < 4; jj++) {
                int idx = tid + jj * 256;
                int r = idx >> 3, ku = idx & 7;
                *(uint4*)&Ws[r * 72 + ku * 8] =
                    *(const uint4*)&wt[(size_t)r * 128 + 64 + ku * 8];
            }
            __syncthreads();
        }
#pragma unroll
        for (int n = 0; n < 8; n++) {
#pragma unroll
            for (int kc = 0; kc < 2; kc++) {
                bf16x8 bfr = *(const bf16x8*)&Ws[(n * 16 + l16) * 72 + kc * 32 + quad * 8];
                acc[n] = __builtin_amdgcn_mfma_f32_16x16x32_bf16(
                    af[c * 2 + kc], bfr, acc[n], 0, 0, 0);
            }
        }
    }

    const int rbase = row0 + wrow + quad * 4;
    float dv[4];
#pragma unroll
    for (int r = 0; r < 4; r++)
        dv[r] = (rbase + r < N) ? dis[rbase + r] : 0.f;
#pragma unroll
    for (int n = 0; n < 8; n++) {
        int col = n * 16 + l16;
#pragma unroll
        for (int r = 0; r < 4; r++) {
            if (rbase + r < N)
                C[(size_t)(rbase + r) * 128 + col] = f2bf(dv[r] * acc[n][r]);
        }
    }
}

// ---- fused agg128 + fc, wave-private tiles (r15-proven): wave wv gathers ITS OWN
// 16 rows (2 nodes/pass x 8 passes), then MFMAs them @ Wfc. No barrier. ----
__global__ __launch_bounds__(256) void aggfc_k(const int* __restrict__ rowptr,
                                               const uint2* __restrict__ meta,
                                               const uint2* __restrict__ h,
                                               const float* __restrict__ dis,
                                               const float* __restrict__ b2,
                                               const unsigned short* __restrict__ wfct,
                                               const float* __restrict__ bfc,
                                               float* __restrict__ out, int N) {
    __shared__ unsigned short h2s[64 * 136];
    const int tid = threadIdx.x;
    const int wv = tid >> 6, lane = tid & 63;
    const int l32 = lane & 31, sub = lane >> 5;
    const int nbase = blockIdx.x * 64;

    // ---- gather phase: wave wv fills rows wv*16 .. wv*16+15 ----
#pragma unroll 2
    for (int p = 0; p < 8; p++) {
        int r = wv * 16 + p * 2 + sub;
        int node = nbase + r;
        float4 acc = make_float4(0.f, 0.f, 0.f, 0.f);
        float d = 0.f;
        if (node < N) {
            d = dis[node];
            uint2 hcu = h[(size_t)node * 32 + l32];
            float2 h0 = bfpair(hcu.x), h1 = bfpair(hcu.y);
            acc.x = h0.x; acc.y = h0.y; acc.z = h1.x; acc.w = h1.y;
            int j = rowptr[node], jend = rowptr[node + 1];
            for (; j + 3 < jend; j += 4) {
                uint2 m0 = meta[j],     m1 = meta[j + 1];
                uint2 m2 = meta[j + 2], m3 = meta[j + 3];
                uint2 g0 = h[(size_t)m0.x * 32 + l32];
                uint2 g1 = h[(size_t)m1.x * 32 + l32];
                uint2 g2 = h[(size_t)m2.x * 32 + l32];
                uint2 g3 = h[(size_t)m3.x * 32 + l32];
                float v0 = __uint_as_float(m0.y), v1 = __uint_as_float(m1.y);
                float v2 = __uint_as_float(m2.y), v3 = __uint_as_float(m3.y);
                float2 a, b;
                a = bfpair(g0.x); b = bfpair(g0.y);
                acc.x = fmaf(v0, a.x, acc.x); acc.y = fmaf(v0, a.y, acc.y);
                acc.z = fmaf(v0, b.x, acc.z); acc.w = fmaf(v0, b.y, acc.w);
                a = bfpair(g1.x); b = bfpair(g1.y);
                acc.x = fmaf(v1, a.x, acc.x); acc.y = fmaf(v1, a.y, acc.y);
                acc.z = fmaf(v1, b.x, acc.z); acc.w = fmaf(v1, b.y, acc.w);
                a = bfpair(g2.x); b = bfpair(g2.y);
                acc.x = fmaf(v2, a.x, acc.x); acc.y = fmaf(v2, a.y, acc.y);
                acc.z = fmaf(v2, b.x, acc.z); acc.w = fmaf(v2, b.y, acc.w);
                a = bfpair(g3.x); b = bfpair(g3.y);
                acc.x = fmaf(v3, a.x, acc.x); acc.y = fmaf(v3, a.y, acc.y);
                acc.z = fmaf(v3, b.x, acc.z); acc.w = fmaf(v3, b.y, acc.w);
            }
            for (; j < jend; j++) {
                uint2 m = meta[j];
                float v = __uint_as_float(m.y);
                uint2 g = h[(size_t)m.x * 32 + l32];
                float2 a = bfpair(g.x), b = bfpair(g.y);
                acc.x = fmaf(v, a.x, acc.x); acc.y = fmaf(v, a.y, acc.y);
                acc.z = fmaf(v, b.x, acc.z); acc.w = fmaf(v, b.y, acc.w);
            }
        }
        float4 bv = ((const float4*)b2)[l32];
        acc.x = fmaxf(fmaf(d, acc.x, bv.x), 0.f);
        acc.y = fmaxf(fmaf(d, acc.y, bv.y), 0.f);
        acc.z = fmaxf(fmaf(d, acc.z, bv.z), 0.f);
        acc.w = fmaxf(fmaf(d, acc.w, bv.w), 0.f);
        if (node >= N) { acc = make_float4(0.f, 0.f, 0.f, 0.f); }
        *(uint2*)&h2s[r * 136 + l32 * 4] =
            make_uint2(packbf(acc.x, acc.y), packbf(acc.z, acc.w));
    }
    // no __syncthreads(): each wave reads back only the rows it wrote

    // ---- fc phase: wave wv handles its rows wv*16..+15 ----
    const int q = lane >> 4, m = lane & 15;
    bf16x8 af[4];
#pragma unroll
    for (int ks = 0; ks < 4; ks++)
        af[ks] = *(const bf16x8*)&h2s[(wv * 16 + m) * 136 + ks * 32 + q * 8];

#pragma unroll
    for (int n = 0; n < 2; n++) {
        f32x4 o = (f32x4)0.f;
#pragma unroll
        for (int ks = 0; ks < 4; ks++) {
            bf16x8 bfr = *(const bf16x8*)&wfct[(size_t)(n * 16 + m) * 128 + ks * 32 + q * 8];
            o = __builtin_amdgcn_mfma_f32_16x16x32_bf16(af[ks], bfr, o, 0, 0, 0);
        }
        int col = n * 16 + m;
        if (col < NCLASS) {
            float bv = bfc[col];
            int r0 = nbase + wv * 16 + q * 4;
#pragma unroll
            for (int r = 0; r < 4; r++) {
                if (r0 + r < N)
                    out[(size_t)(r0 + r) * NCLASS + col] = o[r] + bv;
            }
        }
    }
}

extern "C" void kernel_launch(void* const* d_in, const int* in_sizes, int n_in,
                              void* d_out, int out_size, void* d_ws, size_t ws_size,
                              hipStream_t stream) {
    const float* x   = (const float*)d_in[0];
    const int*   ei  = (const int*)d_in[1];
    const float* ew  = (const float*)d_in[2];
    const float* W1  = (const float*)d_in[3];
    const float* b1  = (const float*)d_in[4];
    const float* W2  = (const float*)d_in[5];
    const float* b2  = (const float*)d_in[6];
    const float* Wfc = (const float*)d_in[7];
    const float* bfc = (const float*)d_in[8];
    float* out = (float*)d_out;

    const int N = NNODES;
    const int* erow = ei;
    const int* ecol = ei + NEDGES;

    // ws layout (float-unit offsets):
    float* fws    = (float*)d_ws;
    float* dis    = fws;                                       // 100000
    int*   rowptr = (int*)(fws + 100000);                      // 100001 (+pad)
    int*   H      = (int*)(fws + 200004);                      // 114856
    int*   incl   = (int*)(fws + 314860);                      // 114856
    int*   aux    = (int*)(fws + 429716);                      // 512
    uint2* rw     = (uint2*)(fws + 430228);                    // 600000 uint2
    unsigned short* lc = (unsigned short*)(fws + 1630228);     // 600000 u16
    uint2* meta   = (uint2*)(fws + 1930228);                   // 600000 uint2
    unsigned short* wt16   = (unsigned short*)(fws + 3130228); // 128*128
    unsigned short* w1t16  = (unsigned short*)(fws + 3138420); // 128*32
    unsigned short* wfct16 = (unsigned short*)(fws + 3140468); // 32*128
    unsigned int*   xp     = (unsigned int*)(fws + 3142516);   // N*16
    unsigned int*   aggx   = (unsigned int*)(fws + 4742516);   // N*16
    unsigned short* hB16   = (unsigned short*)(fws + 6342516); // N*128 bf16 (t2s)

    const int gScan = (NH + 255) / 256;   // 449
    const int gA26  = N / 16;             // 6250
    const int gPrep = 96 + (N * 16 + 255) / 256;
    const int g64   = (N + 63) / 64;      // 1563

    // ---- CSR build (5 kernels) ----
    histA_k<<<NBE, 256, 0, stream>>>(ecol, H);
    scanH1_k<<<gScan, 256, 0, stream>>>(H, incl, aux, NH);
    scan2_k<<<1, 512, 0, stream>>>(aux, gScan);
    partB_k<<<NBE, 256, 0, stream>>>(erow, ecol, ew, incl, H, aux, rw, lc);
    segbp_k<<<NBKT, 256, 0, stream>>>(rw, lc, incl, H, aux, rowptr, dis, meta);

    // ---- prep ----
    prep_k<<<gPrep, 256, 0, stream>>>(W2, W1, Wfc, x, dis, wt16, w1t16, wfct16, xp);

    // ---- layer 1 agg (standalone) -> fused gemm1+gemm2 (64-row, Ws-staged) ----
    agg26_k<<<gA26, 256, 0, stream>>>(rowptr, meta, xp, dis, aggx);
    gemm12_k<<<g64, 256, 0, stream>>>((const unsigned short*)aggx, w1t16, b1,
                                      wt16, dis, hB16, N);

    // ---- fused agg128 + fc (r15 wave-private 2-node, barrier-free) ----
    aggfc_k<<<g64, 256, 0, stream>>>(rowptr, meta, (const uint2*)hB16, dis, b2,
                                     wfct16, bfc, out, N);
}